// Round 1
// baseline (434.984 us; speedup 1.0000x reference)
//
#include <hip/hip_runtime.h>

// Problem constants (from reference): B=8192, A=8, OBS=128, NACT=32, H=256, D=64
#define NROW  65536      // B*A
#define AG    8
#define XD    256        // 2*OBS
#define NACT_ 32
#define HD    256
#define DD    64
#define SCALE 0.125f     // 1/sqrt(D)

// workspace layout (float offsets)
#define WS_MT 0                         // M^T folded matrix: [32][256], scale pre-applied
#define WS_TB 8192                      // t bias: [32]
#define WS_T  8256                      // t: [NROW][32]
#define WS_HV (8256 + NROW * 32)        // hv: [NROW][64]  (pre-relu, wv1_b included)

// ---------------------------------------------------------------------------
// setup: Mt[k][c] = SCALE * sum_d wk_w[d][k] * wq_w[d][c];  tb[k] = SCALE * wk[:,k]·wq_b
// ---------------------------------------------------------------------------
__global__ __launch_bounds__(256) void k_setup(const float* __restrict__ wq_w,
                                               const float* __restrict__ wq_b,
                                               const float* __restrict__ wk_w,
                                               float* ws) {
    int gid = blockIdx.x * 256 + threadIdx.x;   // [0, 8192)
    int k = gid >> 8, c = gid & 255;
    float acc = 0.f;
#pragma unroll 8
    for (int d = 0; d < 64; ++d)
        acc = fmaf(wk_w[d * 32 + k], wq_w[d * 256 + c], acc);
    ws[WS_MT + k * 256 + c] = SCALE * acc;
    if (gid < 32) {
        float b = 0.f;
#pragma unroll 8
        for (int d = 0; d < 64; ++d)
            b = fmaf(wk_w[d * 32 + gid], wq_b[d], b);
        ws[WS_TB + gid] = SCALE * b;
    }
}

// ---------------------------------------------------------------------------
// K1: per row n compute t[n][32] = Mt @ concat(o,o_next)[n] + tb
//             and     hv[n][64] = Wv1h @ h[n] + wv1_b      (pre-relu)
// lane = row, wave = output slice (8 k's / 16 d's). Weights via wave-uniform
// scalar loads (readfirstlane on wave id). No LDS, no barriers.
// ---------------------------------------------------------------------------
__global__ __launch_bounds__(256, 4) void k1(const float* __restrict__ o,
                                             const float* __restrict__ onx,
                                             const float* __restrict__ h,
                                             const float* __restrict__ wv1,
                                             const float* __restrict__ wv1b,
                                             const float* __restrict__ wsc,
                                             float* ws) {
    const int lane = threadIdx.x & 63;
    const int wid  = __builtin_amdgcn_readfirstlane(threadIdx.x >> 6);
    const int n    = blockIdx.x * 64 + lane;

    // ---- t: 8 outputs, k = wid*8 .. wid*8+7 ----
    const float* Mt = wsc + WS_MT + wid * (8 * 256);
    float tacc[8];
#pragma unroll
    for (int kk = 0; kk < 8; ++kk) tacc[kk] = wsc[WS_TB + wid * 8 + kk];

    const float4* o4 = (const float4*)(o + n * 128);
#pragma unroll 4
    for (int c4 = 0; c4 < 32; ++c4) {          // x[0..127] = o
        float4 v = o4[c4];
#pragma unroll
        for (int kk = 0; kk < 8; ++kk) {
            const float* w = Mt + kk * 256 + c4 * 4;
            tacc[kk] = fmaf(w[0], v.x, tacc[kk]);
            tacc[kk] = fmaf(w[1], v.y, tacc[kk]);
            tacc[kk] = fmaf(w[2], v.z, tacc[kk]);
            tacc[kk] = fmaf(w[3], v.w, tacc[kk]);
        }
    }
    const float4* x4 = (const float4*)(onx + n * 128);
#pragma unroll 4
    for (int c4 = 0; c4 < 32; ++c4) {          // x[128..255] = o_next
        float4 v = x4[c4];
#pragma unroll
        for (int kk = 0; kk < 8; ++kk) {
            const float* w = Mt + kk * 256 + 128 + c4 * 4;
            tacc[kk] = fmaf(w[0], v.x, tacc[kk]);
            tacc[kk] = fmaf(w[1], v.y, tacc[kk]);
            tacc[kk] = fmaf(w[2], v.z, tacc[kk]);
            tacc[kk] = fmaf(w[3], v.w, tacc[kk]);
        }
    }
    float* tout = ws + WS_T + n * 32 + wid * 8;
    ((float4*)tout)[0] = make_float4(tacc[0], tacc[1], tacc[2], tacc[3]);
    ((float4*)tout)[1] = make_float4(tacc[4], tacc[5], tacc[6], tacc[7]);

    // ---- hv: 16 outputs, d = wid*16 .. +15 ----
    float va[16];
#pragma unroll
    for (int dd = 0; dd < 16; ++dd) va[dd] = wv1b[wid * 16 + dd];

    const float4* h4 = (const float4*)(h + n * 256);
#pragma unroll 2
    for (int c4 = 0; c4 < 64; ++c4) {
        float4 v = h4[c4];
#pragma unroll
        for (int dd = 0; dd < 16; ++dd) {
            const float* w = wv1 + (wid * 16 + dd) * 288 + c4 * 4;  // h-part cols [0,256)
            va[dd] = fmaf(w[0], v.x, va[dd]);
            va[dd] = fmaf(w[1], v.y, va[dd]);
            va[dd] = fmaf(w[2], v.z, va[dd]);
            va[dd] = fmaf(w[3], v.w, va[dd]);
        }
    }
    float* hout = ws + WS_HV + n * 64 + wid * 16;
#pragma unroll
    for (int q = 0; q < 4; ++q)
        ((float4*)hout)[q] = make_float4(va[4 * q], va[4 * q + 1], va[4 * q + 2], va[4 * q + 3]);
}

// ---------------------------------------------------------------------------
// K2: per 64-row group (8 batches): scores = t·a, masked softmax, then
// s[n] = sum_j attn * relu(hv[g(n,j)] + Wv1a a[n,j]),  q[n] = Wv2 s[n] + b2.
// lane = row; waves split j (scores), d-slice (value), e-slice (output).
// ---------------------------------------------------------------------------
__global__ __launch_bounds__(256, 3) void k2(const float* __restrict__ act,
                                             const float* __restrict__ wv1,
                                             const float* __restrict__ wv2,
                                             const float* __restrict__ wv2b,
                                             const float* __restrict__ ws,
                                             float* __restrict__ out) {
    __shared__ float t_s[64 * 36];    // t rows, padded stride 36
    __shared__ float hv_s[64 * 68];   // hv rows, j-major swizzle, stride 68
    __shared__ float at_s[64 * 9];    // scores -> attn, stride 9
    __shared__ float s_s[64 * 68];    // s rows, stride 68

    const int tid  = threadIdx.x;
    const int lane = tid & 63;
    const int wid  = __builtin_amdgcn_readfirstlane(tid >> 6);
    const int n0   = blockIdx.x * 64;

    // ---- stage t, hv (coalesced) ----
    {
        const float4* tg = (const float4*)(ws + WS_T + n0 * 32);
        for (int i = tid; i < 512; i += 256) {
            int row = i >> 3, c4 = i & 7;
            *(float4*)&t_s[row * 36 + c4 * 4] = tg[row * 8 + c4];
        }
        const float4* hg = (const float4*)(ws + WS_HV + n0 * 64);
        for (int i = tid; i < 1024; i += 256) {
            int row = i >> 4, c4 = i & 15;
            int rs = ((row & 7) << 3) | (row >> 3);   // [j][batch] swizzle
            *(float4*)&hv_s[rs * 68 + c4 * 4] = hg[row * 16 + c4];
        }
    }
    __syncthreads();

    // ---- scores: wave w computes j = 2w, 2w+1 for all 64 rows ----
    {
        float tr[32];
#pragma unroll
        for (int q = 0; q < 8; ++q) {
            float4 v = *(const float4*)&t_s[lane * 36 + q * 4];
            tr[4 * q + 0] = v.x; tr[4 * q + 1] = v.y; tr[4 * q + 2] = v.z; tr[4 * q + 3] = v.w;
        }
        const float* arow = act + (n0 + lane) * 256;
#pragma unroll
        for (int jj = 0; jj < 2; ++jj) {
            int j = wid * 2 + jj;
            float sc = 0.f;
#pragma unroll
            for (int c4 = 0; c4 < 8; ++c4) {
                float4 a = *(const float4*)(arow + j * 32 + c4 * 4);
                sc = fmaf(tr[c4 * 4 + 0], a.x, sc);
                sc = fmaf(tr[c4 * 4 + 1], a.y, sc);
                sc = fmaf(tr[c4 * 4 + 2], a.z, sc);
                sc = fmaf(tr[c4 * 4 + 3], a.w, sc);
            }
            at_s[lane * 9 + j] = sc;
        }
    }
    __syncthreads();

    // ---- softmax (diag masked) — wave 0, one row per lane ----
    if (tid < 64) {
        const int diag = tid & 7;
        float sc[8];
#pragma unroll
        for (int j = 0; j < 8; ++j) sc[j] = at_s[tid * 9 + j];
        float m = -1e30f;
#pragma unroll
        for (int j = 0; j < 8; ++j) if (j != diag) m = fmaxf(m, sc[j]);
        float p[8], sum = 0.f;
#pragma unroll
        for (int j = 0; j < 8; ++j) {
            p[j] = (j == diag) ? 0.f : __expf(sc[j] - m);
            sum += p[j];
        }
        float inv = 1.f / sum;
#pragma unroll
        for (int j = 0; j < 8; ++j) at_s[tid * 9 + j] = p[j] * inv;
    }
    __syncthreads();

    // ---- value: wave w owns d in [w*16, w*16+16) ----
    {
        float s_acc[16];
#pragma unroll
        for (int dd = 0; dd < 16; ++dd) s_acc[dd] = 0.f;
        const float* arow = act + (n0 + lane) * 256;
        const int bswz = lane >> 3;
#pragma unroll 2
        for (int j = 0; j < 8; ++j) {
            float ha[16];
#pragma unroll
            for (int dd = 0; dd < 16; ++dd) ha[dd] = 0.f;
#pragma unroll
            for (int c4 = 0; c4 < 8; ++c4) {
                float4 a = *(const float4*)(arow + j * 32 + c4 * 4);
#pragma unroll
                for (int dd = 0; dd < 16; ++dd) {
                    const float* w = wv1 + (wid * 16 + dd) * 288 + 256 + c4 * 4; // action cols
                    ha[dd] = fmaf(w[0], a.x, ha[dd]);
                    ha[dd] = fmaf(w[1], a.y, ha[dd]);
                    ha[dd] = fmaf(w[2], a.z, ha[dd]);
                    ha[dd] = fmaf(w[3], a.w, ha[dd]);
                }
            }
            float at = at_s[lane * 9 + j];
            const float* hvp = &hv_s[(j * 8 + bswz) * 68 + wid * 16];
#pragma unroll
            for (int q = 0; q < 4; ++q) {
                float4 hvv = *(const float4*)(hvp + q * 4);
                float h0 = fmaxf(hvv.x + ha[4 * q + 0], 0.f);
                float h1 = fmaxf(hvv.y + ha[4 * q + 1], 0.f);
                float h2 = fmaxf(hvv.z + ha[4 * q + 2], 0.f);
                float h3 = fmaxf(hvv.w + ha[4 * q + 3], 0.f);
                s_acc[4 * q + 0] = fmaf(at, h0, s_acc[4 * q + 0]);
                s_acc[4 * q + 1] = fmaf(at, h1, s_acc[4 * q + 1]);
                s_acc[4 * q + 2] = fmaf(at, h2, s_acc[4 * q + 2]);
                s_acc[4 * q + 3] = fmaf(at, h3, s_acc[4 * q + 3]);
            }
        }
        float* sp = &s_s[lane * 68 + wid * 16];
#pragma unroll
        for (int q = 0; q < 4; ++q)
            *(float4*)(sp + q * 4) = make_float4(s_acc[4 * q], s_acc[4 * q + 1],
                                                 s_acc[4 * q + 2], s_acc[4 * q + 3]);
    }
    __syncthreads();

    // ---- q = Wv2 s + b2 : wave w owns e in [w*8, w*8+8) ----
    {
        float qa[8];
#pragma unroll
        for (int ee = 0; ee < 8; ++ee) qa[ee] = wv2b[wid * 8 + ee];
#pragma unroll 4
        for (int d4 = 0; d4 < 16; ++d4) {
            float4 sv = *(const float4*)&s_s[lane * 68 + d4 * 4];
#pragma unroll
            for (int ee = 0; ee < 8; ++ee) {
                const float* w = wv2 + (wid * 8 + ee) * 64 + d4 * 4;
                qa[ee] = fmaf(w[0], sv.x, qa[ee]);
                qa[ee] = fmaf(w[1], sv.y, qa[ee]);
                qa[ee] = fmaf(w[2], sv.z, qa[ee]);
                qa[ee] = fmaf(w[3], sv.w, qa[ee]);
            }
        }
        float* op = out + (n0 + lane) * 32 + wid * 8;
        ((float4*)op)[0] = make_float4(qa[0], qa[1], qa[2], qa[3]);
        ((float4*)op)[1] = make_float4(qa[4], qa[5], qa[6], qa[7]);
    }
}

extern "C" void kernel_launch(void* const* d_in, const int* in_sizes, int n_in,
                              void* d_out, int out_size, void* d_ws, size_t ws_size,
                              hipStream_t stream) {
    const float* o     = (const float*)d_in[0];
    const float* onx   = (const float*)d_in[1];
    const float* h     = (const float*)d_in[2];
    const float* act   = (const float*)d_in[3];
    const float* wq_w  = (const float*)d_in[4];
    const float* wq_b  = (const float*)d_in[5];
    const float* wk_w  = (const float*)d_in[6];
    // d_in[7] = wk_b: adds a per-row constant to all scores -> softmax-invariant (diag masked); unused
    const float* wv1_w = (const float*)d_in[8];
    const float* wv1_b = (const float*)d_in[9];
    const float* wv2_w = (const float*)d_in[10];
    const float* wv2_b = (const float*)d_in[11];
    float* out = (float*)d_out;
    float* ws  = (float*)d_ws;   // needs ~25.2 MB

    k_setup<<<32, 256, 0, stream>>>(wq_w, wq_b, wk_w, ws);
    k1<<<NROW / 64, 256, 0, stream>>>(o, onx, h, wv1_w, wv1_b, ws, ws);
    k2<<<NROW / 64, 256, 0, stream>>>(act, wv1_w, wv2_w, wv2_b, ws, out);
}

// Round 2
// 315.111 us; speedup vs baseline: 1.3804x; 1.3804x over previous
//
#include <hip/hip_runtime.h>

// B=8192, A=8, OBS=128, NACT=32, H=256, D=64 ; N = 65536 rows
#define SCALE 0.125f

// ws layout (float offsets)
#define WS_MT 0        // folded M^T: [32][256], scale applied
#define WS_TB 8192     // [32]

// smem layout (float offsets), total 15712 floats = 62848 B (<= 64 KB static)
#define HV_O   0                  // hv: [64][68]  (pre-relu, bias included)
#define HV_S   68
#define T_O    4352               // t: [64][36]
#define T_S    36
#define AT_O   6656               // scores/attn: [64][9]
#define AT_S   9
#define W2_O   7232               // wv2 staged: [32][64]
#define POOL   9280
// phase A pool: XS [4][520] (x||h rows), PH [4][4][64], PT [8][4][32]
#define XS_O   POOL               // 2080 f
#define XS_S   520
#define PH_O   (POOL + 2080)      // 1024 f
#define PT_O   (POOL + 3104)     // 1024 f
// phase B pool (aliases A pool): AS [8][260], SS [64][68]
#define AS_O   POOL               // 2080 f
#define AS_S   260
#define SS_O   (POOL + 2080)      // 4352 f
#define SMEM_F (POOL + 6432)      // 15712

// ---------------------------------------------------------------------------
// setup: Mt[k][c] = SCALE * sum_d wk_w[d][k]*wq_w[d][c];  tb[k] = SCALE*wk[:,k]·wq_b
// (wk_b adds a j-independent per-row constant to scores -> softmax-invariant)
// ---------------------------------------------------------------------------
__global__ __launch_bounds__(256) void k_setup(const float* __restrict__ wq_w,
                                               const float* __restrict__ wq_b,
                                               const float* __restrict__ wk_w,
                                               float* ws) {
    int gid = blockIdx.x * 256 + threadIdx.x;   // [0, 8192)
    int k = gid >> 8, c = gid & 255;
    float acc = 0.f;
#pragma unroll 8
    for (int d = 0; d < 64; ++d)
        acc = fmaf(wk_w[d * 32 + k], wq_w[d * 256 + c], acc);
    ws[WS_MT + k * 256 + c] = SCALE * acc;
    if (gid < 32) {
        float b = 0.f;
#pragma unroll 8
        for (int d = 0; d < 64; ++d)
            b = fmaf(wk_w[d * 32 + gid], wq_b[d], b);
        ws[WS_TB + gid] = SCALE * b;
    }
}

// ---------------------------------------------------------------------------
// Fused: per block = 64 rows (8 batches).
// Phase A: weight-stationary (VGPR) hv/t, activations staged->LDS broadcast.
// Then scores -> masked softmax -> value (weight-stationary ha) -> Wv2.
// ---------------------------------------------------------------------------
__global__ __launch_bounds__(256, 2) void fused(
    const float* __restrict__ o, const float* __restrict__ onx,
    const float* __restrict__ h, const float* __restrict__ act,
    const float* __restrict__ wv1, const float* __restrict__ wv1b,
    const float* __restrict__ wv2, const float* __restrict__ wv2b,
    const float* __restrict__ ws, float* __restrict__ out)
{
    __shared__ __align__(16) float sm[SMEM_F];
    const int tid  = threadIdx.x;
    const int lane = tid & 63;
    const int wid  = __builtin_amdgcn_readfirstlane(tid >> 6);
    const int lh   = lane >> 5;      // lane half (t K-sub)
    const int kk   = lane & 31;
    const int n0   = blockIdx.x * 64;

    // ---- stage wv2 into LDS (coalesced) ----
    {
        const float4* wg = (const float4*)wv2;
        float4* wd = (float4*)&sm[W2_O];
        wd[tid]       = wg[tid];
        wd[tid + 256] = wg[tid + 256];
    }

    // ---- per-lane stationary weights ----
    float w_hv[64];   // lane = d: Wv1h[d][wid*64 .. +64)
    {
        const float* p = wv1 + lane * 288 + wid * 64;
#pragma unroll
        for (int c4 = 0; c4 < 16; ++c4) {
            float4 v = *(const float4*)(p + c4 * 4);
            w_hv[4*c4]=v.x; w_hv[4*c4+1]=v.y; w_hv[4*c4+2]=v.z; w_hv[4*c4+3]=v.w;
        }
    }
    float w_t[32];    // lane = (k, lh): Mt[k][wid*64 + lh*32 .. +32)
    {
        const float* p = ws + WS_MT + kk * 256 + wid * 64 + lh * 32;
#pragma unroll
        for (int c4 = 0; c4 < 8; ++c4) {
            float4 v = *(const float4*)(p + c4 * 4);
            w_t[4*c4]=v.x; w_t[4*c4+1]=v.y; w_t[4*c4+2]=v.z; w_t[4*c4+3]=v.w;
        }
    }
    const float vb  = wv1b[lane];          // bias for d = tid&63 in reduce
    const float tbv = ws[WS_TB + kk];      // bias for k = tid&31 in reduce

    // ---- Phase A: 16 chunks x 4 rows ----
    float4 pf0, pf1;
    {   // prefetch chunk 0: x = [o row | onx row] (128 quads), h (256 quads)
        if (tid < 128) pf0 = ((const float4*)o)[(size_t)n0 * 32 + tid];
        else           pf0 = ((const float4*)onx)[(size_t)n0 * 32 + (tid - 128)];
        pf1 = ((const float4*)h)[(size_t)n0 * 64 + tid];
    }
    for (int ch = 0; ch < 16; ++ch) {
        __syncthreads();                       // (a) prev compute done
        // stage chunk ch into XS: row layout [o 128][onx 128][h 256][pad 8]
        if (tid < 128) {
            int r = tid >> 5, c4 = tid & 31;
            *(float4*)&sm[XS_O + r * XS_S + c4 * 4] = pf0;
        } else {
            int r = (tid >> 5) & 3, c4 = tid & 31;
            *(float4*)&sm[XS_O + r * XS_S + 128 + c4 * 4] = pf0;
        }
        {
            int r = tid >> 6, c4 = tid & 63;
            *(float4*)&sm[XS_O + r * XS_S + 256 + c4 * 4] = pf1;
        }
        if (ch > 0) {                          // reduce chunk ch-1 (PH/PT -> HV/T)
            int c = ch - 1;
            {
                int r = tid >> 6, d = tid & 63;
                float s = sm[PH_O + r*64 + d] + sm[PH_O + 256 + r*64 + d]
                        + sm[PH_O + 512 + r*64 + d] + sm[PH_O + 768 + r*64 + d];
                sm[HV_O + (c*4 + r) * HV_S + d] = s + vb;
            }
            if (tid < 128) {
                int r = tid >> 5, k = tid & 31;
                float s = 0.f;
#pragma unroll
                for (int p = 0; p < 8; ++p) s += sm[PT_O + p*128 + r*32 + k];
                sm[T_O + (c*4 + r) * T_S + k] = s + tbv;
            }
        }
        if (ch < 15) {                         // prefetch chunk ch+1
            int base = n0 + (ch + 1) * 4;
            if (tid < 128) pf0 = ((const float4*)o)[(size_t)base * 32 + tid];
            else           pf0 = ((const float4*)onx)[(size_t)base * 32 + (tid - 128)];
            pf1 = ((const float4*)h)[(size_t)base * 64 + tid];
        }
        __syncthreads();                       // (b) staging visible, partials free
        // compute partials for 4 rows
#pragma unroll
        for (int r = 0; r < 4; ++r) {
            const float* hp = &sm[XS_O + r * XS_S + 256 + wid * 64];
            float acc = 0.f;
#pragma unroll
            for (int c = 0; c < 64; ++c) acc = fmaf(w_hv[c], hp[c], acc);
            sm[PH_O + (wid*4 + r) * 64 + lane] = acc;
            const float* xp = &sm[XS_O + r * XS_S + wid * 64 + lh * 32];
            float ta = 0.f;
#pragma unroll
            for (int c = 0; c < 32; ++c) ta = fmaf(w_t[c], xp[c], ta);
            sm[PT_O + (wid*2 + lh) * 128 + r * 32 + kk] = ta;
        }
    }
    __syncthreads();
    {   // reduce last chunk (15)
        {
            int r = tid >> 6, d = tid & 63;
            float s = sm[PH_O + r*64 + d] + sm[PH_O + 256 + r*64 + d]
                    + sm[PH_O + 512 + r*64 + d] + sm[PH_O + 768 + r*64 + d];
            sm[HV_O + (60 + r) * HV_S + d] = s + vb;
        }
        if (tid < 128) {
            int r = tid >> 5, k = tid & 31;
            float s = 0.f;
#pragma unroll
            for (int p = 0; p < 8; ++p) s += sm[PT_O + p*128 + r*32 + k];
            sm[T_O + (60 + r) * T_S + k] = s + tbv;
        }
    }
    __syncthreads();

    // ---- scores: wave w computes j = 2w, 2w+1 for all 64 rows (lane=row) ----
    {
        float tr[32];
#pragma unroll
        for (int c4 = 0; c4 < 8; ++c4) {
            float4 v = *(const float4*)&sm[T_O + lane * T_S + c4 * 4];
            tr[4*c4]=v.x; tr[4*c4+1]=v.y; tr[4*c4+2]=v.z; tr[4*c4+3]=v.w;
        }
        const float* arow = act + (size_t)(n0 + lane) * 256;
#pragma unroll
        for (int jj = 0; jj < 2; ++jj) {
            int j = wid * 2 + jj;
            float sc = 0.f;
#pragma unroll
            for (int c4 = 0; c4 < 8; ++c4) {
                float4 a = *(const float4*)(arow + j * 32 + c4 * 4);
                sc = fmaf(tr[4*c4],   a.x, sc);
                sc = fmaf(tr[4*c4+1], a.y, sc);
                sc = fmaf(tr[4*c4+2], a.z, sc);
                sc = fmaf(tr[4*c4+3], a.w, sc);
            }
            sm[AT_O + lane * AT_S + j] = sc;
        }
    }
    // prefetch phase-B group 0 act rows
    float4 pa0 = ((const float4*)act)[(size_t)n0 * 64 + tid];
    float4 pa1 = ((const float4*)act)[(size_t)n0 * 64 + tid + 256];
    __syncthreads();

    // ---- softmax (diag masked), one row per lane of wave 0 ----
    if (tid < 64) {
        const int diag = tid & 7;
        float s[8];
#pragma unroll
        for (int j = 0; j < 8; ++j) s[j] = sm[AT_O + tid * AT_S + j];
        float m = -1e30f;
#pragma unroll
        for (int j = 0; j < 8; ++j) if (j != diag) m = fmaxf(m, s[j]);
        float e[8], sum = 0.f;
#pragma unroll
        for (int j = 0; j < 8; ++j) { e[j] = (j == diag) ? 0.f : __expf(s[j] - m); sum += e[j]; }
        float inv = 1.f / sum;
#pragma unroll
        for (int j = 0; j < 8; ++j) sm[AT_O + tid * AT_S + j] = e[j] * inv;
    }
    __syncthreads();

    // ---- Phase B: value accumulation, lane = d, 8 groups x 8 rows ----
    float wA[32];   // Wv1a[d=lane][0..32)
    {
        const float* p = wv1 + lane * 288 + 256;
#pragma unroll
        for (int c4 = 0; c4 < 8; ++c4) {
            float4 v = *(const float4*)(p + c4 * 4);
            wA[4*c4]=v.x; wA[4*c4+1]=v.y; wA[4*c4+2]=v.z; wA[4*c4+3]=v.w;
        }
    }
    for (int g = 0; g < 8; ++g) {
        {   // stage act rows [g*8, g*8+8) -> AS
            *(float4*)&sm[AS_O + (tid >> 6) * AS_S + (tid & 63) * 4] = pa0;
            int q = tid + 256;
            *(float4*)&sm[AS_O + (q >> 6) * AS_S + (q & 63) * 4] = pa1;
        }
        if (g < 7) {
            size_t base = (size_t)(n0 + (g + 1) * 8) * 64;
            pa0 = ((const float4*)act)[base + tid];
            pa1 = ((const float4*)act)[base + tid + 256];
        }
        __syncthreads();
#pragma unroll
        for (int rr = 0; rr < 2; ++rr) {
            int rl = wid * 2 + rr;         // row within 8-group
            int r  = g * 8 + rl;           // row within block
            int bb = r & ~7;               // batch base row
            float at[8];
#pragma unroll
            for (int j = 0; j < 8; ++j) at[j] = sm[AT_O + r * AT_S + j];
            float sacc = 0.f;
#pragma unroll
            for (int j = 0; j < 8; ++j) {
                const float* ap = &sm[AS_O + rl * AS_S + j * 32];
                float ha = 0.f;
#pragma unroll
                for (int c = 0; c < 32; ++c) ha = fmaf(wA[c], ap[c], ha);
                float hv = sm[HV_O + (bb + j) * HV_S + lane];
                sacc = fmaf(at[j], fmaxf(hv + ha, 0.f), sacc);
            }
            sm[SS_O + r * HV_S + lane] = sacc;
        }
        __syncthreads();
    }

    // ---- Wv2: lane = row, wave w owns e in [w*8, w*8+8) ----
    {
        float qa[8];
#pragma unroll
        for (int e = 0; e < 8; ++e) qa[e] = wv2b[wid * 8 + e];
#pragma unroll 4
        for (int d4 = 0; d4 < 16; ++d4) {
            float4 sv = *(const float4*)&sm[SS_O + lane * HV_S + d4 * 4];
#pragma unroll
            for (int e = 0; e < 8; ++e) {
                float4 wv = *(const float4*)&sm[W2_O + (wid * 8 + e) * 64 + d4 * 4];
                qa[e] = fmaf(wv.x, sv.x, qa[e]);
                qa[e] = fmaf(wv.y, sv.y, qa[e]);
                qa[e] = fmaf(wv.z, sv.z, qa[e]);
                qa[e] = fmaf(wv.w, sv.w, qa[e]);
            }
        }
        float* op = out + (size_t)(n0 + lane) * 32 + wid * 8;
        ((float4*)op)[0] = make_float4(qa[0], qa[1], qa[2], qa[3]);
        ((float4*)op)[1] = make_float4(qa[4], qa[5], qa[6], qa[7]);
    }
}

extern "C" void kernel_launch(void* const* d_in, const int* in_sizes, int n_in,
                              void* d_out, int out_size, void* d_ws, size_t ws_size,
                              hipStream_t stream) {
    const float* o     = (const float*)d_in[0];
    const float* onx   = (const float*)d_in[1];
    const float* h     = (const float*)d_in[2];
    const float* act   = (const float*)d_in[3];
    const float* wq_w  = (const float*)d_in[4];
    const float* wq_b  = (const float*)d_in[5];
    const float* wk_w  = (const float*)d_in[6];
    // d_in[7] = wk_b unused (softmax-invariant, diagonal masked)
    const float* wv1_w = (const float*)d_in[8];
    const float* wv1_b = (const float*)d_in[9];
    const float* wv2_w = (const float*)d_in[10];
    const float* wv2_b = (const float*)d_in[11];
    float* out = (float*)d_out;
    float* ws  = (float*)d_ws;   // needs ~33 KB

    k_setup<<<32, 256, 0, stream>>>(wq_w, wq_b, wk_w, ws);
    fused<<<1024, 256, 0, stream>>>(o, onx, h, act, wv1_w, wv1_b, wv2_w, wv2_b, ws, out);
}

// Round 3
// 284.690 us; speedup vs baseline: 1.5279x; 1.1069x over previous
//
#include <hip/hip_runtime.h>

// B=8192, A=8, OBS=128, NACT=32, H=256, D=64 ; N = 65536 rows
typedef __attribute__((ext_vector_type(8))) short bf16x8;   // 8 bf16 (4 VGPRs)
typedef __attribute__((ext_vector_type(4))) float f32x4;

#define MFMA(A, B, C) __builtin_amdgcn_mfma_f32_16x16x32_bf16((A), (B), (C), 0, 0, 0)

// ---- ws byte offsets: weights pre-split to bf16 hi/lo planes, [out][k] layout ----
#define OFF_TB    0          // f32 [32]   folded t bias
#define OFF_WT_H  128        // bf16 [32][256]  Mt = SCALE*wk^T*wq (k_out major)
#define OFF_WT_L  16512
#define OFF_WHV_H 32896      // bf16 [64][256]  wv1 h-part
#define OFF_WHV_L 65664
#define OFF_WA_H  98432      // bf16 [64][32]   wv1 action-part
#define OFF_WA_L  102528

// ---- LDS layout (bytes), total 58880 ----
#define SM_P0   0        // 20480: phase A split-X double-buffer / phase B act buffer
#define SM_HV   20480    // f32 [64][68]
#define SM_T    37888    // f32 [64][36]; aliased later as W2 f32 [32][64]
#define SM_AT   47104    // f32 [8][64]  scores -> attn
#define SM_SS   49152    // bf16 [64][76] s rows
#define SM_TOT  58880

__device__ __forceinline__ unsigned short f2bf(float v) {   // RNE
    unsigned u = __builtin_bit_cast(unsigned, v);
    return (unsigned short)((u + 0x7fffu + ((u >> 16) & 1u)) >> 16);
}
__device__ __forceinline__ float bf2f(unsigned short b) {
    return __builtin_bit_cast(float, ((unsigned)b) << 16);
}
__device__ __forceinline__ ushort2 splitf(float v) {        // (hi, lo residual)
    unsigned short h = f2bf(v);
    unsigned short l = f2bf(v - bf2f(h));
    return make_ushort2(h, l);
}

// ---------------------------------------------------------------------------
// setup: fold Mt = SCALE*wk^T*wq (+bias), split all weights into bf16 hi/lo
// planes in fragment-native [out][k] layout. wk_b is softmax-invariant (diag
// masked) and dropped — verified in round 1.
// ---------------------------------------------------------------------------
__global__ __launch_bounds__(256) void k_setup(const float* __restrict__ wq_w,
                                               const float* __restrict__ wq_b,
                                               const float* __restrict__ wk_w,
                                               const float* __restrict__ wv1,
                                               char* __restrict__ ws) {
    int gid = blockIdx.x * 256 + threadIdx.x;
    if (gid < 8192) {                              // Mt[k][c]
        int k = gid >> 8, c = gid & 255;
        float acc = 0.f;
#pragma unroll 8
        for (int d = 0; d < 64; ++d) acc = fmaf(wk_w[d * 32 + k], wq_w[d * 256 + c], acc);
        ushort2 s = splitf(0.125f * acc);
        ((unsigned short*)(ws + OFF_WT_H))[gid] = s.x;
        ((unsigned short*)(ws + OFF_WT_L))[gid] = s.y;
    } else if (gid < 24576) {                      // wv1 h-part [d][c]
        int i = gid - 8192;
        ushort2 s = splitf(wv1[(i >> 8) * 288 + (i & 255)]);
        ((unsigned short*)(ws + OFF_WHV_H))[i] = s.x;
        ((unsigned short*)(ws + OFF_WHV_L))[i] = s.y;
    } else if (gid < 26624) {                      // wv1 action-part [d][k]
        int i = gid - 24576;
        ushort2 s = splitf(wv1[(i >> 5) * 288 + 256 + (i & 31)]);
        ((unsigned short*)(ws + OFF_WA_H))[i] = s.x;
        ((unsigned short*)(ws + OFF_WA_L))[i] = s.y;
    } else if (gid < 26656) {                      // tb
        int k = gid - 26624;
        float b = 0.f;
#pragma unroll 8
        for (int d = 0; d < 64; ++d) b = fmaf(wk_w[d * 32 + k], wq_b[d], b);
        ((float*)(ws + OFF_TB))[k] = 0.125f * b;
    }
}

// ---------------------------------------------------------------------------
// Fused kernel, block = 64 rows (8 batches). All GEMMs via split-bf16 MFMA
// (3 mfma/product: AhBh + AhBl + AlBh; residual ~2^-18 — fp32-class).
// Orientation: D[m=output][n=row]; A-frag = weights (global, [out][k]),
// B-frag = activations (LDS, [row][k] so lane n=l&15 reads its row's k-slice).
// ---------------------------------------------------------------------------
__global__ __launch_bounds__(256, 2) void fused(
    const float* __restrict__ o, const float* __restrict__ onx,
    const float* __restrict__ h, const float* __restrict__ act,
    const float* __restrict__ wv1b, const float* __restrict__ wv2,
    const float* __restrict__ wv2b, const char* __restrict__ ws,
    float* __restrict__ out)
{
    __shared__ __align__(16) char sm[SM_TOT];
    short* P0 = (short*)(sm + SM_P0);
    float* HV = (float*)(sm + SM_HV);
    float* T  = (float*)(sm + SM_T);
    float* AT = (float*)(sm + SM_AT);
    short* SS = (short*)(sm + SM_SS);

    const int tid  = threadIdx.x;
    const int lane = tid & 63;
    const int wid  = tid >> 6;
    const int l15  = lane & 15;
    const int quad = lane >> 4;
    const int n0   = blockIdx.x * 64;

    const f32x4 zv = {0.f, 0.f, 0.f, 0.f};
    f32x4 acc_hv[4] = {zv, zv, zv, zv};
    f32x4 acc_t[2]  = {zv, zv};

    // chunk ch: 0-3 = o (k 0..127), 4-7 = onx (k 128..255), 8-15 = h (k 0..255)
    auto chunk_load = [&](int ch, int i) -> float4 {
        int row = i >> 3, c4 = i & 7;
        if (ch < 4)  return ((const float4*)o)  [(size_t)(n0 + row) * 32 + ch * 8 + c4];
        if (ch < 8)  return ((const float4*)onx)[(size_t)(n0 + row) * 32 + (ch - 4) * 8 + c4];
        return ((const float4*)h)[(size_t)(n0 + row) * 64 + (ch - 8) * 8 + c4];
    };
    auto chunk_store = [&](int buf, int i, float4 v) {
        int row = i >> 3, c4 = i & 7;
        short* XH = P0 + buf * 5120;     // [64][40] bf16 hi
        short* XL = XH + 2560;           // [64][40] bf16 lo
        ushort2 s0 = splitf(v.x), s1 = splitf(v.y), s2 = splitf(v.z), s3 = splitf(v.w);
        *(ushort4*)&XH[row * 40 + c4 * 4] = make_ushort4(s0.x, s1.x, s2.x, s3.x);
        *(ushort4*)&XL[row * 40 + c4 * 4] = make_ushort4(s0.y, s1.y, s2.y, s3.y);
    };

    // ---- Phase A: 16 k-chunks of 32, double-buffered staging ----
    {
        float4 p0 = chunk_load(0, tid), p1 = chunk_load(0, tid + 256);
        chunk_store(0, tid, p0);
        chunk_store(0, tid + 256, p1);
        for (int ch = 0; ch < 16; ++ch) {
            __syncthreads();
            if (ch < 15) { p0 = chunk_load(ch + 1, tid); p1 = chunk_load(ch + 1, tid + 256); }
            {
                const short* XH = P0 + (ch & 1) * 5120;
                const short* XL = XH + 2560;
                int brow = wid * 16 + l15;                 // wave w owns rows 16w..16w+15
                bf16x8 Bh = *(const bf16x8*)&XH[brow * 40 + quad * 8];
                bf16x8 Bl = *(const bf16x8*)&XL[brow * 40 + quad * 8];
                if (ch < 8) {                              // x-chunk -> t outputs
#pragma unroll
                    for (int mt = 0; mt < 2; ++mt) {
                        int off = ((mt * 16 + l15) * 256 + ch * 32 + quad * 8) * 2;
                        bf16x8 Ah = *(const bf16x8*)(ws + OFF_WT_H + off);
                        bf16x8 Al = *(const bf16x8*)(ws + OFF_WT_L + off);
                        acc_t[mt] = MFMA(Ah, Bh, acc_t[mt]);
                        acc_t[mt] = MFMA(Ah, Bl, acc_t[mt]);
                        acc_t[mt] = MFMA(Al, Bh, acc_t[mt]);
                    }
                } else {                                   // h-chunk -> hv outputs
#pragma unroll
                    for (int mt = 0; mt < 4; ++mt) {
                        int off = ((mt * 16 + l15) * 256 + (ch - 8) * 32 + quad * 8) * 2;
                        bf16x8 Ah = *(const bf16x8*)(ws + OFF_WHV_H + off);
                        bf16x8 Al = *(const bf16x8*)(ws + OFF_WHV_L + off);
                        acc_hv[mt] = MFMA(Ah, Bh, acc_hv[mt]);
                        acc_hv[mt] = MFMA(Ah, Bl, acc_hv[mt]);
                        acc_hv[mt] = MFMA(Al, Bh, acc_hv[mt]);
                    }
                }
            }
            if (ch < 15) {
                chunk_store((ch + 1) & 1, tid, p0);
                chunk_store((ch + 1) & 1, tid + 256, p1);
            }
        }
    }
    // epilogue A: C/D layout col=lane&15 -> row n, row=quad*4+reg -> output m
    {
        int erow = wid * 16 + l15;
        const float* tb = (const float*)(ws + OFF_TB);
#pragma unroll
        for (int mt = 0; mt < 4; ++mt) {
            int d0 = mt * 16 + quad * 4;
            float4 b = *(const float4*)&wv1b[d0];
            f32x4 a = acc_hv[mt];
            *(float4*)&HV[erow * 68 + d0] =
                make_float4(a[0] + b.x, a[1] + b.y, a[2] + b.z, a[3] + b.w);
        }
#pragma unroll
        for (int mt = 0; mt < 2; ++mt) {
            int k0 = mt * 16 + quad * 4;
            float4 b = *(const float4*)&tb[k0];
            f32x4 a = acc_t[mt];
            *(float4*)&T[erow * 36 + k0] =
                make_float4(a[0] + b.x, a[1] + b.y, a[2] + b.z, a[3] + b.w);
        }
    }
    __syncthreads();

    // ---- scores: lane=row, wave w computes j = 2w, 2w+1 (fp32 VALU) ----
    {
        float tr[32];
#pragma unroll
        for (int c4 = 0; c4 < 8; ++c4) {
            float4 v = *(const float4*)&T[lane * 36 + c4 * 4];
            tr[c4*4+0]=v.x; tr[c4*4+1]=v.y; tr[c4*4+2]=v.z; tr[c4*4+3]=v.w;
        }
        const float* arow = act + (size_t)(n0 + lane) * 256;
#pragma unroll
        for (int jj = 0; jj < 2; ++jj) {
            int j = wid * 2 + jj;
            float sc = 0.f;
#pragma unroll
            for (int c4 = 0; c4 < 8; ++c4) {
                float4 a = *(const float4*)(arow + j * 32 + c4 * 4);
                sc = fmaf(tr[c4*4+0], a.x, sc);
                sc = fmaf(tr[c4*4+1], a.y, sc);
                sc = fmaf(tr[c4*4+2], a.z, sc);
                sc = fmaf(tr[c4*4+3], a.w, sc);
            }
            AT[j * 64 + lane] = sc;
        }
    }
    __syncthreads();

    // ---- softmax (diag masked), wave 0, one row per lane ----
    if (tid < 64) {
        int diag = tid & 7;
        float sc[8];
#pragma unroll
        for (int j = 0; j < 8; ++j) sc[j] = AT[j * 64 + tid];
        float mx = -1e30f;
#pragma unroll
        for (int j = 0; j < 8; ++j) if (j != diag) mx = fmaxf(mx, sc[j]);
        float e[8], sum = 0.f;
#pragma unroll
        for (int j = 0; j < 8; ++j) { e[j] = (j == diag) ? 0.f : __expf(sc[j] - mx); sum += e[j]; }
        float inv = 1.f / sum;
#pragma unroll
        for (int j = 0; j < 8; ++j) AT[j * 64 + tid] = e[j] * inv;
    }

    // stage W2 over dead T region; hoist phase-B A-frags (K=32 fits entirely)
    float* W2 = T;
    {
        const float4* wg = (const float4*)wv2;
        ((float4*)W2)[tid]       = wg[tid];
        ((float4*)W2)[tid + 256] = wg[tid + 256];
    }
    bf16x8 WAh[4], WAl[4];
#pragma unroll
    for (int mt = 0; mt < 4; ++mt) {
        int off = ((mt * 16 + l15) * 32 + quad * 8) * 2;
        WAh[mt] = *(const bf16x8*)(ws + OFF_WA_H + off);
        WAl[mt] = *(const bf16x8*)(ws + OFF_WA_L + off);
    }

    auto act_stage = [&](int g) {   // 128 nj-rows x 32 -> split bf16 [128][40]
        const float4* ag = (const float4*)(act + (size_t)(n0 + g * 16) * 256);
        short* AH = P0; short* AL = P0 + 5120;
#pragma unroll
        for (int q = 0; q < 4; ++q) {
            int i = tid + q * 256;
            int njr = i >> 3, c4 = i & 7;
            float4 v = ag[njr * 8 + c4];
            ushort2 s0 = splitf(v.x), s1 = splitf(v.y), s2 = splitf(v.z), s3 = splitf(v.w);
            *(ushort4*)&AH[njr * 40 + c4 * 4] = make_ushort4(s0.x, s1.x, s2.x, s3.x);
            *(ushort4*)&AL[njr * 40 + c4 * 4] = make_ushort4(s0.y, s1.y, s2.y, s3.y);
        }
    };
    act_stage(0);
    __syncthreads();

    // ---- Phase B: 4 groups x 128 nj-rows; ha = Wv1a·a via MFMA, then
    //      s[n][d] = sum_j attn*relu(hv+ha) (shfl-reduce over 8 j-lanes) ----
    for (int g = 0; g < 4; ++g) {
        const short* AH = P0; const short* AL = P0 + 5120;
        f32x4 accB[8];
#pragma unroll
        for (int i = 0; i < 8; ++i) accB[i] = zv;
#pragma unroll
        for (int nt = 0; nt < 2; ++nt) {
            int njr = wid * 32 + nt * 16 + l15;
            bf16x8 Bh = *(const bf16x8*)&AH[njr * 40 + quad * 8];
            bf16x8 Bl = *(const bf16x8*)&AL[njr * 40 + quad * 8];
#pragma unroll
            for (int mt = 0; mt < 4; ++mt) {
                f32x4 a = accB[nt * 4 + mt];
                a = MFMA(WAh[mt], Bh, a);
                a = MFMA(WAh[mt], Bl, a);
                a = MFMA(WAl[mt], Bh, a);
                accB[nt * 4 + mt] = a;
            }
        }
#pragma unroll
        for (int nt = 0; nt < 2; ++nt) {
            int njr  = wid * 32 + nt * 16 + l15;
            int nb   = g * 16 + (njr >> 3);        // block-local output row
            int j    = njr & 7;
            int hrow = (nb & ~7) + j;              // h_rep row = batch base + j
            float at = AT[j * 64 + nb];
#pragma unroll
            for (int mt = 0; mt < 4; ++mt) {
                int d0 = mt * 16 + quad * 4;
                float4 hv4 = *(const float4*)&HV[hrow * 68 + d0];
                f32x4 a = accB[nt * 4 + mt];
                float v0 = at * fmaxf(a[0] + hv4.x, 0.f);
                float v1 = at * fmaxf(a[1] + hv4.y, 0.f);
                float v2 = at * fmaxf(a[2] + hv4.z, 0.f);
                float v3 = at * fmaxf(a[3] + hv4.w, 0.f);
#pragma unroll
                for (int m = 1; m <= 4; m <<= 1) {
                    v0 += __shfl_xor(v0, m);
                    v1 += __shfl_xor(v1, m);
                    v2 += __shfl_xor(v2, m);
                    v3 += __shfl_xor(v3, m);
                }
                if (j == 0)
                    *(ushort4*)&SS[nb * 76 + d0] =
                        make_ushort4(f2bf(v0), f2bf(v1), f2bf(v2), f2bf(v3));
            }
        }
        __syncthreads();
        if (g < 3) act_stage(g + 1);
        __syncthreads();
    }

    // ---- Wv2: lane=row, wave w owns e in [8w, 8w+8) ----
    {
        float s[64];
#pragma unroll
        for (int q = 0; q < 16; ++q) {
            ushort4 u = *(const ushort4*)&SS[lane * 76 + q * 4];
            s[q*4+0] = bf2f(u.x); s[q*4+1] = bf2f(u.y);
            s[q*4+2] = bf2f(u.z); s[q*4+3] = bf2f(u.w);
        }
        float qa[8];
#pragma unroll
        for (int e = 0; e < 8; ++e) qa[e] = wv2b[wid * 8 + e];
#pragma unroll
        for (int d4 = 0; d4 < 16; ++d4) {
#pragma unroll
            for (int e = 0; e < 8; ++e) {
                float4 w = *(const float4*)&W2[(wid * 8 + e) * 64 + d4 * 4];
                qa[e] = fmaf(w.x, s[d4*4+0], qa[e]);
                qa[e] = fmaf(w.y, s[d4*4+1], qa[e]);
                qa[e] = fmaf(w.z, s[d4*4+2], qa[e]);
                qa[e] = fmaf(w.w, s[d4*4+3], qa[e]);
            }
        }
        float* op = out + (size_t)(n0 + lane) * 32 + wid * 8;
        ((float4*)op)[0] = make_float4(qa[0], qa[1], qa[2], qa[3]);
        ((float4*)op)[1] = make_float4(qa[4], qa[5], qa[6], qa[7]);
    }
}

extern "C" void kernel_launch(void* const* d_in, const int* in_sizes, int n_in,
                              void* d_out, int out_size, void* d_ws, size_t ws_size,
                              hipStream_t stream) {
    const float* o     = (const float*)d_in[0];
    const float* onx   = (const float*)d_in[1];
    const float* h     = (const float*)d_in[2];
    const float* act   = (const float*)d_in[3];
    const float* wq_w  = (const float*)d_in[4];
    const float* wq_b  = (const float*)d_in[5];
    const float* wk_w  = (const float*)d_in[6];
    // d_in[7] = wk_b unused (softmax-invariant, diagonal masked)
    const float* wv1_w = (const float*)d_in[8];
    const float* wv1_b = (const float*)d_in[9];
    const float* wv2_w = (const float*)d_in[10];
    const float* wv2_b = (const float*)d_in[11];
    float* out = (float*)d_out;
    char* ws   = (char*)d_ws;   // needs ~105 KB

    k_setup<<<105, 256, 0, stream>>>(wq_w, wq_b, wk_w, wv1_w, ws);
    fused<<<1024, 256, 0, stream>>>(o, onx, h, act, wv1_b, wv2_w, wv2_b, ws, out);
}

// Round 4
// 278.183 us; speedup vs baseline: 1.5637x; 1.0234x over previous
//
#include <hip/hip_runtime.h>

// B=8192, A=8, OBS=128, NACT=32, H=256, D=64 ; N = 65536 rows
typedef __attribute__((ext_vector_type(8))) short bf16x8;   // 8 bf16 (4 VGPRs)
typedef __attribute__((ext_vector_type(4))) float f32x4;

#define MFMA(A, B, C) __builtin_amdgcn_mfma_f32_16x16x32_bf16((A), (B), (C), 0, 0, 0)

// ---- ws byte offsets: weights pre-split to bf16 hi/lo planes, [out][k] layout ----
#define OFF_TB    0          // f32 [32]   folded t bias
#define OFF_WT_H  128        // bf16 [32][256]  Mt = SCALE*wk^T*wq
#define OFF_WT_L  16512
#define OFF_WHV_H 32896      // bf16 [64][256]  wv1 h-part
#define OFF_WHV_L 65664
#define OFF_WA_H  98432      // bf16 [64][32]   wv1 action-part
#define OFF_WA_L  102528     // end 106624

// ---- LDS layout (bytes), total 46592 -> 3 blocks/CU ----
#define SM_HV   0        // f32 [64][68]   17408
#define SM_T    17408    // f32 [64][36]    9216
#define SM_AT   26624    // f32 [8][64]     2048
#define SM_SS   28672    // bf16 [64][76]   9728
#define SM_W2   38400    // f32 [32][64]    8192
#define SM_TOT  46592

__device__ __forceinline__ unsigned short f2bf(float v) {   // RNE
    unsigned u = __builtin_bit_cast(unsigned, v);
    return (unsigned short)((u + 0x7fffu + ((u >> 16) & 1u)) >> 16);
}
__device__ __forceinline__ float bf2f(unsigned short b) {
    return __builtin_bit_cast(float, ((unsigned)b) << 16);
}
__device__ __forceinline__ ushort2 splitf(float v) {        // (hi, lo residual)
    unsigned short h = f2bf(v);
    unsigned short l = f2bf(v - bf2f(h));
    return make_ushort2(h, l);
}
__device__ __forceinline__ void split8(float4 a, float4 b, bf16x8& hi, bf16x8& lo) {
    float v[8] = {a.x, a.y, a.z, a.w, b.x, b.y, b.z, b.w};
    bf16x8 H, L;
#pragma unroll
    for (int i = 0; i < 8; ++i) {
        ushort2 s = splitf(v[i]);
        H[i] = (short)s.x;
        L[i] = (short)s.y;
    }
    hi = H; lo = L;
}

// ---------------------------------------------------------------------------
// setup: fold Mt = SCALE*wk^T*wq (+bias), split all weights into bf16 hi/lo
// planes in fragment-native [out][k] layout. wk_b dropped (softmax-invariant,
// diagonal masked — verified round 1).
// ---------------------------------------------------------------------------
__global__ __launch_bounds__(256) void k_setup(const float* __restrict__ wq_w,
                                               const float* __restrict__ wq_b,
                                               const float* __restrict__ wk_w,
                                               const float* __restrict__ wv1,
                                               char* __restrict__ ws) {
    int gid = blockIdx.x * 256 + threadIdx.x;
    if (gid < 8192) {                              // Mt[k][c]
        int k = gid >> 8, c = gid & 255;
        float acc = 0.f;
#pragma unroll 8
        for (int d = 0; d < 64; ++d) acc = fmaf(wk_w[d * 32 + k], wq_w[d * 256 + c], acc);
        ushort2 s = splitf(0.125f * acc);
        ((unsigned short*)(ws + OFF_WT_H))[gid] = s.x;
        ((unsigned short*)(ws + OFF_WT_L))[gid] = s.y;
    } else if (gid < 24576) {                      // wv1 h-part [d][c]
        int i = gid - 8192;
        ushort2 s = splitf(wv1[(i >> 8) * 288 + (i & 255)]);
        ((unsigned short*)(ws + OFF_WHV_H))[i] = s.x;
        ((unsigned short*)(ws + OFF_WHV_L))[i] = s.y;
    } else if (gid < 26624) {                      // wv1 action-part [d][k]
        int i = gid - 24576;
        ushort2 s = splitf(wv1[(i >> 5) * 288 + 256 + (i & 31)]);
        ((unsigned short*)(ws + OFF_WA_H))[i] = s.x;
        ((unsigned short*)(ws + OFF_WA_L))[i] = s.y;
    } else if (gid < 26656) {                      // tb
        int k = gid - 26624;
        float b = 0.f;
#pragma unroll 8
        for (int d = 0; d < 64; ++d) b = fmaf(wk_w[d * 32 + k], wq_b[d], b);
        ((float*)(ws + OFF_TB))[k] = 0.125f * b;
    }
}

// ---------------------------------------------------------------------------
// Fused, block = 64 rows (8 batches). Split-bf16 MFMA (AhBh+AhBl+AlBh).
// Activations loaded DIRECTLY from global in B-fragment layout (lane n=l&15
// owns row, quad owns k-slice of 8 consecutive floats) — no staging LDS, no
// phase barriers. Only 4 barriers total (cross-wave hand-offs via LDS).
// ---------------------------------------------------------------------------
__global__ __launch_bounds__(256, 3) void fused(
    const float* __restrict__ o, const float* __restrict__ onx,
    const float* __restrict__ h, const float* __restrict__ act,
    const float* __restrict__ wv1b, const float* __restrict__ wv2,
    const float* __restrict__ wv2b, const char* __restrict__ ws,
    float* __restrict__ out)
{
    __shared__ __align__(16) char sm[SM_TOT];
    float* HV = (float*)(sm + SM_HV);
    float* T  = (float*)(sm + SM_T);
    float* AT = (float*)(sm + SM_AT);
    short* SS = (short*)(sm + SM_SS);
    float* W2 = (float*)(sm + SM_W2);

    const int tid  = threadIdx.x;
    const int lane = tid & 63;
    const int wid  = tid >> 6;
    const int l15  = lane & 15;
    const int quad = lane >> 4;
    const int n0   = blockIdx.x * 64;

    // stage W2 (consumed only after the last barrier)
    {
        const float4* wg = (const float4*)wv2;
        ((float4*)W2)[tid]       = wg[tid];
        ((float4*)W2)[tid + 256] = wg[tid + 256];
    }

    const f32x4 zv = {0.f, 0.f, 0.f, 0.f};
    f32x4 acc_hv[4] = {zv, zv, zv, zv};
    f32x4 acc_t[2]  = {zv, zv};

    const int myrow = n0 + wid * 16 + l15;    // phase-A fragment row of this lane

    // ---- Phase A: barrier-free MFMA stream over 16 K-chunks of 32 ----
    // x-chunks (t outputs): k 0..255 = [o | o_next]
#pragma unroll
    for (int ch = 0; ch < 8; ++ch) {
        const float* src = (ch < 4)
            ? o   + (size_t)myrow * 128 + ch * 32 + quad * 8
            : onx + (size_t)myrow * 128 + (ch - 4) * 32 + quad * 8;
        float4 v0 = *(const float4*)src;
        float4 v1 = *(const float4*)(src + 4);
        bf16x8 Bh, Bl;
        split8(v0, v1, Bh, Bl);
#pragma unroll
        for (int mt = 0; mt < 2; ++mt) {
            int off = ((mt * 16 + l15) * 256 + ch * 32 + quad * 8) * 2;
            bf16x8 Ah = *(const bf16x8*)(ws + OFF_WT_H + off);
            bf16x8 Al = *(const bf16x8*)(ws + OFF_WT_L + off);
            acc_t[mt] = MFMA(Ah, Bh, acc_t[mt]);
            acc_t[mt] = MFMA(Ah, Bl, acc_t[mt]);
            acc_t[mt] = MFMA(Al, Bh, acc_t[mt]);
        }
    }
    // h-chunks (hv outputs)
#pragma unroll
    for (int ch = 0; ch < 8; ++ch) {
        const float* src = h + (size_t)myrow * 256 + ch * 32 + quad * 8;
        float4 v0 = *(const float4*)src;
        float4 v1 = *(const float4*)(src + 4);
        bf16x8 Bh, Bl;
        split8(v0, v1, Bh, Bl);
#pragma unroll
        for (int mt = 0; mt < 4; ++mt) {
            int off = ((mt * 16 + l15) * 256 + ch * 32 + quad * 8) * 2;
            bf16x8 Ah = *(const bf16x8*)(ws + OFF_WHV_H + off);
            bf16x8 Al = *(const bf16x8*)(ws + OFF_WHV_L + off);
            acc_hv[mt] = MFMA(Ah, Bh, acc_hv[mt]);
            acc_hv[mt] = MFMA(Ah, Bl, acc_hv[mt]);
            acc_hv[mt] = MFMA(Al, Bh, acc_hv[mt]);
        }
    }
    // epilogue A: C/D layout col=lane&15 -> row n, row=quad*4+reg -> output m
    {
        int erow = wid * 16 + l15;
        const float* tb = (const float*)(ws + OFF_TB);
#pragma unroll
        for (int mt = 0; mt < 4; ++mt) {
            int d0 = mt * 16 + quad * 4;
            float4 b = *(const float4*)&wv1b[d0];
            f32x4 a = acc_hv[mt];
            *(float4*)&HV[erow * 68 + d0] =
                make_float4(a[0] + b.x, a[1] + b.y, a[2] + b.z, a[3] + b.w);
        }
#pragma unroll
        for (int mt = 0; mt < 2; ++mt) {
            int k0 = mt * 16 + quad * 4;
            float4 b = *(const float4*)&tb[k0];
            f32x4 a = acc_t[mt];
            *(float4*)&T[erow * 36 + k0] =
                make_float4(a[0] + b.x, a[1] + b.y, a[2] + b.z, a[3] + b.w);
        }
    }
    __syncthreads();                               // barrier 1: T/HV visible

    // ---- scores: lane=row, wave w computes j = 2w, 2w+1 (fp32 VALU) ----
    {
        float tr[32];
#pragma unroll
        for (int c4 = 0; c4 < 8; ++c4) {
            float4 v = *(const float4*)&T[lane * 36 + c4 * 4];
            tr[c4*4+0]=v.x; tr[c4*4+1]=v.y; tr[c4*4+2]=v.z; tr[c4*4+3]=v.w;
        }
        const float* arow = act + (size_t)(n0 + lane) * 256;
#pragma unroll
        for (int jj = 0; jj < 2; ++jj) {
            int j = wid * 2 + jj;
            float sc = 0.f;
#pragma unroll
            for (int c4 = 0; c4 < 8; ++c4) {
                float4 a = *(const float4*)(arow + j * 32 + c4 * 4);
                sc = fmaf(tr[c4*4+0], a.x, sc);
                sc = fmaf(tr[c4*4+1], a.y, sc);
                sc = fmaf(tr[c4*4+2], a.z, sc);
                sc = fmaf(tr[c4*4+3], a.w, sc);
            }
            AT[j * 64 + lane] = sc;
        }
    }
    // hoist phase-B A-frags here (latency hidden under softmax barriers)
    bf16x8 WAh[4], WAl[4];
#pragma unroll
    for (int mt = 0; mt < 4; ++mt) {
        int off = ((mt * 16 + l15) * 32 + quad * 8) * 2;
        WAh[mt] = *(const bf16x8*)(ws + OFF_WA_H + off);
        WAl[mt] = *(const bf16x8*)(ws + OFF_WA_L + off);
    }
    __syncthreads();                               // barrier 2: AT (scores) visible

    // ---- softmax (diag masked), wave 0, one row per lane ----
    if (tid < 64) {
        int diag = tid & 7;
        float sc[8];
#pragma unroll
        for (int j = 0; j < 8; ++j) sc[j] = AT[j * 64 + tid];
        float mx = -1e30f;
#pragma unroll
        for (int j = 0; j < 8; ++j) if (j != diag) mx = fmaxf(mx, sc[j]);
        float e[8], sum = 0.f;
#pragma unroll
        for (int j = 0; j < 8; ++j) { e[j] = (j == diag) ? 0.f : __expf(sc[j] - mx); sum += e[j]; }
        float inv = 1.f / sum;
#pragma unroll
        for (int j = 0; j < 8; ++j) AT[j * 64 + tid] = e[j] * inv;
    }
    __syncthreads();                               // barrier 3: attn visible

    // ---- Phase B: barrier-free; act fragments direct from global ----
    // njr = (local row nb, attended j); ha = Wv1a·a via MFMA, then
    // s[nb][d] = sum_j attn*relu(hv+ha) via shfl-reduce over the 8 j-lanes.
#pragma unroll
    for (int g = 0; g < 4; ++g) {
#pragma unroll
        for (int nt = 0; nt < 2; ++nt) {
            int njr = wid * 32 + nt * 16 + l15;
            int nb  = g * 16 + (njr >> 3);
            int j   = njr & 7;
            const float* ap = act + (size_t)(n0 + nb) * 256 + j * 32 + quad * 8;
            float4 v0 = *(const float4*)ap;
            float4 v1 = *(const float4*)(ap + 4);
            bf16x8 Bh, Bl;
            split8(v0, v1, Bh, Bl);
            f32x4 accB[4] = {zv, zv, zv, zv};
#pragma unroll
            for (int mt = 0; mt < 4; ++mt) {
                accB[mt] = MFMA(WAh[mt], Bh, accB[mt]);
                accB[mt] = MFMA(WAh[mt], Bl, accB[mt]);
                accB[mt] = MFMA(WAl[mt], Bh, accB[mt]);
            }
            int hrow = (nb & ~7) + j;              // h_rep row = batch base + j
            float at = AT[j * 64 + nb];
#pragma unroll
            for (int mt = 0; mt < 4; ++mt) {
                int d0 = mt * 16 + quad * 4;
                float4 hv4 = *(const float4*)&HV[hrow * 68 + d0];
                float r0 = at * fmaxf(accB[mt][0] + hv4.x, 0.f);
                float r1 = at * fmaxf(accB[mt][1] + hv4.y, 0.f);
                float r2 = at * fmaxf(accB[mt][2] + hv4.z, 0.f);
                float r3 = at * fmaxf(accB[mt][3] + hv4.w, 0.f);
#pragma unroll
                for (int m = 1; m <= 4; m <<= 1) {
                    r0 += __shfl_xor(r0, m);
                    r1 += __shfl_xor(r1, m);
                    r2 += __shfl_xor(r2, m);
                    r3 += __shfl_xor(r3, m);
                }
                if (j == 0)
                    *(ushort4*)&SS[nb * 76 + d0] =
                        make_ushort4(f2bf(r0), f2bf(r1), f2bf(r2), f2bf(r3));
            }
        }
    }
    __syncthreads();                               // barrier 4: SS visible

    // ---- Wv2: lane=row, wave w owns e in [8w, 8w+8) ----
    {
        float s[64];
#pragma unroll
        for (int q = 0; q < 16; ++q) {
            ushort4 u = *(const ushort4*)&SS[lane * 76 + q * 4];
            s[q*4+0] = bf2f(u.x); s[q*4+1] = bf2f(u.y);
            s[q*4+2] = bf2f(u.z); s[q*4+3] = bf2f(u.w);
        }
        float qa[8];
#pragma unroll
        for (int e = 0; e < 8; ++e) qa[e] = wv2b[wid * 8 + e];
#pragma unroll
        for (int d4 = 0; d4 < 16; ++d4) {
#pragma unroll
            for (int e = 0; e < 8; ++e) {
                float4 w = *(const float4*)&W2[(wid * 8 + e) * 64 + d4 * 4];
                qa[e] = fmaf(w.x, s[d4*4+0], qa[e]);
                qa[e] = fmaf(w.y, s[d4*4+1], qa[e]);
                qa[e] = fmaf(w.z, s[d4*4+2], qa[e]);
                qa[e] = fmaf(w.w, s[d4*4+3], qa[e]);
            }
        }
        float* op = out + (size_t)(n0 + lane) * 32 + wid * 8;
        ((float4*)op)[0] = make_float4(qa[0], qa[1], qa[2], qa[3]);
        ((float4*)op)[1] = make_float4(qa[4], qa[5], qa[6], qa[7]);
    }
}

extern "C" void kernel_launch(void* const* d_in, const int* in_sizes, int n_in,
                              void* d_out, int out_size, void* d_ws, size_t ws_size,
                              hipStream_t stream) {
    const float* o     = (const float*)d_in[0];
    const float* onx   = (const float*)d_in[1];
    const float* h     = (const float*)d_in[2];
    const float* act   = (const float*)d_in[3];
    const float* wq_w  = (const float*)d_in[4];
    const float* wq_b  = (const float*)d_in[5];
    const float* wk_w  = (const float*)d_in[6];
    // d_in[7] = wk_b unused (softmax-invariant, diagonal masked)
    const float* wv1_w = (const float*)d_in[8];
    const float* wv1_b = (const float*)d_in[9];
    const float* wv2_w = (const float*)d_in[10];
    const float* wv2_b = (const float*)d_in[11];
    float* out = (float*)d_out;
    char* ws   = (char*)d_ws;   // needs ~105 KB

    k_setup<<<105, 256, 0, stream>>>(wq_w, wq_b, wk_w, wv1_w, ws);
    fused<<<1024, 256, 0, stream>>>(o, onx, h, act, wv1_b, wv2_w, wv2_b, ws, out);
}